// Round 6
// baseline (169.033 us; speedup 1.0000x reference)
//
#include <hip/hip_runtime.h>
#include <hip/hip_bf16.h>
#include <hip/hip_fp16.h>
#include <math.h>

#define NK 256
#define NT 128
#define NC 32
#define ND 10
#define NSPK 1000000
#define LOG2PI 1.8378770664093453f
#define NCHUNK ((NSPK + 255) / 256)   // 3907
#define GRID 1024                     // 4 blocks/CU x 256 CUs, all co-resident

#define FSTR 36                       // dwords per LDS row (32 data + 4 pad)
#define LDS_DW (256 * FSTR)           // 9216 dw = 36 KB, shared by feat & logits

typedef __attribute__((ext_vector_type(8))) short short8;
typedef __attribute__((ext_vector_type(4))) float floatx4;
typedef __attribute__((ext_vector_type(4))) int intx4;

union FragCvt { intx4 i; short8 s; };
union H2Cvt { int i; __half2 h; };

// ws layout:
//   [0,8)      double acc
//   [8,12)     uint done-counter
//   [12,16)    uint work-queue head
//   [64,320)   float cpack[64] : [c]=cst_c, [32+c]=w99_c
//   [1024,..)  int wt[64][32]  : bf16-pair-packed W, rows 0..31 hi, 32..63 lo
//   [16384,..) __half pisT[NK*NT][32]   (fp16 rows, 64 B each)

__device__ inline unsigned pack_bf16(float a, float b) {
  __hip_bfloat16 ha = __float2bfloat16(a), hb = __float2bfloat16(b);
  unsigned short ua, ub;
  __builtin_memcpy(&ua, &ha, 2);
  __builtin_memcpy(&ub, &hb, 2);
  return (unsigned)ua | ((unsigned)ub << 16);
}

// ============================ PREP =========================================
__global__ void prep_kernel(const float* __restrict__ y,
                            const float* __restrict__ means,
                            const float* __restrict__ covs,
                            const float* __restrict__ b_mu,
                            const float* __restrict__ b_ls,
                            const float* __restrict__ beta_mu,
                            const float* __restrict__ beta_ls,
                            int* __restrict__ wt,
                            float* __restrict__ cpack,
                            __half* __restrict__ pisT,
                            double* __restrict__ acc,
                            unsigned int* __restrict__ counter,
                            unsigned int* __restrict__ queue) {
  int blk = blockIdx.x;
  int tid = threadIdx.x;

  if (blk == 0) {
    // ---- per-component coefficients, fully in place (no scratch) ----------
    int c = tid;
    if (c >= NC) return;

    float M[ND][ND];
    #pragma unroll
    for (int i = 0; i < ND; ++i)
      #pragma unroll
      for (int j = 0; j < ND; ++j)
        M[i][j] = covs[c * ND * ND + i * ND + j];

    // Cholesky, lower triangle in place
    float logdet = 0.f;
    #pragma unroll
    for (int j = 0; j < ND; ++j) {
      float d = M[j][j];
      #pragma unroll
      for (int k = 0; k < ND; ++k) if (k < j) d -= M[j][k] * M[j][k];
      float sq = sqrtf(d);
      M[j][j] = sq;
      logdet += 2.f * __logf(sq);
      float inv = 1.f / sq;
      #pragma unroll
      for (int i = 0; i < ND; ++i) {
        if (i > j) {
          float s2 = M[i][j];
          #pragma unroll
          for (int k = 0; k < ND; ++k) if (k < j) s2 -= M[i][k] * M[j][k];
          M[i][j] = s2 * inv;
        }
      }
    }

    // invert lower triangle in place: M(lower) := L^-1
    #pragma unroll
    for (int j = 0; j < ND; ++j) {
      M[j][j] = 1.f / M[j][j];
      #pragma unroll
      for (int i = 0; i < ND; ++i) {
        if (i > j) {
          float s2 = 0.f;
          #pragma unroll
          for (int k = 0; k < ND; ++k) if (k >= j && k < i) s2 += M[i][k] * M[k][j];
          M[i][j] = -s2 / M[i][i];
        }
      }
    }

    // P = Li^T Li : off-diag -> upper triangle of M, diag -> pd[]
    float pd[ND];
    #pragma unroll
    for (int i = 0; i < ND; ++i) {
      #pragma unroll
      for (int jj = 0; jj < ND; ++jj) {
        if (jj >= i) {
          float s2 = 0.f;
          #pragma unroll
          for (int k = 0; k < ND; ++k) if (k >= jj) s2 += M[k][i] * M[k][jj];
          if (jj > i) M[i][jj] = s2;
          else pd[i] = s2;
        }
      }
    }

    float mu[ND], q[ND];
    #pragma unroll
    for (int i = 0; i < ND; ++i) mu[i] = means[c * ND + i];
    float muPmu = 0.f;
    #pragma unroll
    for (int i = 0; i < ND; ++i) {
      float a2 = pd[i] * mu[i];
      #pragma unroll
      for (int j = 0; j < ND; ++j) {
        if (j < i) a2 += M[j][i] * mu[j];
        if (j > i) a2 += M[i][j] * mu[j];
      }
      q[i] = a2;
      muPmu += mu[i] * a2;
    }
    float cst = -0.5f * ((float)ND * LOG2PI + logdet + muPmu);

    // K=64 coefficient vector: 54 pairs (all i<=j except (9,9)) + 10 linear
    float wv[64];
    int p = 0;
    #pragma unroll
    for (int i = 0; i < ND; ++i)
      #pragma unroll
      for (int j = 0; j < ND; ++j)
        if (j >= i && !(i == 9 && j == 9))
          wv[p++] = (i == j) ? -0.5f * pd[i] : -M[i][j];
    #pragma unroll
    for (int i = 0; i < ND; ++i) wv[54 + i] = q[i];

    // hi/lo split, bf16-pair pack; packed rows of 32 dwords (128B)
    #pragma unroll
    for (int j = 0; j < 32; ++j) {
      float a = wv[2 * j], b = wv[2 * j + 1];
      float ah = __bfloat162float(__float2bfloat16(a));
      float bh = __bfloat162float(__float2bfloat16(b));
      wt[c * 32 + j] = (int)pack_bf16(ah, bh);
      wt[(32 + c) * 32 + j] = (int)pack_bf16(a - ah, b - bh);
    }
    cpack[c] = cst;
    cpack[32 + c] = -0.5f * pd[9];   // w99

  } else if (blk == 1) {
    // ---- prior - q scalar terms -> plain-store acc, init counters ---------
    float local = 0.f;
    for (int i = tid; i < NC; i += 256)
      local += fmaf(-0.5f * b_mu[i], b_mu[i], b_ls[i]);
    for (int i = tid; i < NC * NT; i += 256)
      local += fmaf(-0.5f * beta_mu[i], beta_mu[i], beta_ls[i]);
    #pragma unroll
    for (int off = 32; off > 0; off >>= 1) local += __shfl_down(local, off);
    __shared__ float red[4];
    if ((tid & 63) == 0) red[tid >> 6] = local;
    __syncthreads();
    if (tid == 0) {
      acc[0] = (double)(red[0] + red[1] + red[2] + red[3]);
      counter[0] = 0u;
      queue[0] = GRID;                // dynamic chunks start after static ones
    }

  } else {
    // ---- log-softmax pis table, fp16, [k*NT+t][c] contiguous --------------
    int id = (blk - 2) * 256 + tid;          // id = k*NT + t
    int t = id & (NT - 1);
    float yv = y[id];
    float v[NC];
    float m = -1e30f;
    #pragma unroll
    for (int c = 0; c < NC; ++c) {
      v[c] = fmaf(beta_mu[c * NT + t], yv, b_mu[c]);
      m = fmaxf(m, v[c]);
    }
    float ssum = 0.f;
    #pragma unroll
    for (int c = 0; c < NC; ++c) ssum += __expf(v[c] - m);
    float lz = m + __logf(ssum);
    __half* outp = pisT + (size_t)id * NC;
    #pragma unroll
    for (int c = 0; c < NC; ++c) outp[c] = __float2half(v[c] - lz);
  }
}

// ============================ MAIN (persistent MFMA) =======================
__global__ void __launch_bounds__(256)
__attribute__((amdgpu_waves_per_eu(4, 4)))
spike_kernel(const float* __restrict__ s,
             const int* __restrict__ ks,
             const int* __restrict__ ts,
             const int* __restrict__ wt,
             const float* __restrict__ cpack,
             const __half* __restrict__ pisT,
             double* __restrict__ acc,
             unsigned int* __restrict__ counter,
             unsigned int* __restrict__ queue,
             float* __restrict__ out) {
  __shared__ int lds[LDS_DW];        // 36 KB: feat then logits, stride FSTR
  __shared__ float red[4];
  __shared__ int nextc_sh;           // block-uniform work-queue broadcast

  int tid = threadIdx.x;
  int wv_ = tid >> 6, L = tid & 63;
  int r = L & 15, q = L >> 4;

  // B-frags (W hi+lo) from global -> registers, once per block
  FragCvt bf[2][2][2];   // [h][nt][kstep]
  #pragma unroll
  for (int h = 0; h < 2; ++h)
    #pragma unroll
    for (int nt = 0; nt < 2; ++nt)
      #pragma unroll
      for (int ks2 = 0; ks2 < 2; ++ks2)
        bf[h][nt][ks2].i =
            *(const intx4*)&wt[(h * 32 + nt * 16 + r) * 32 + ks2 * 16 + q * 4];

  float lse_sum = 0.f;

  // ---- first (static) chunk loads, clamped ----
  int chunk = blockIdx.x;
  float svc[ND];
  int ktc;
  {
    int n = chunk * 256 + tid;
    int nc = n < NSPK ? n : (NSPK - 1);
    const float2* srow = (const float2*)(s + (size_t)nc * ND);
    #pragma unroll
    for (int i = 0; i < 5; ++i) {
      float2 v2 = srow[i];
      svc[2 * i] = v2.x;
      svc[2 * i + 1] = v2.y;
    }
    ktc = ks[nc] * NT + ts[nc];
  }

  while (chunk < NCHUNK) {
    int ncur = chunk * 256 + tid;

    __syncthreads();   // previous epilogue's LDS reads complete

    // build K=64 bf16 feature row, packed+stored in 8-element windows
    {
      int rb = tid * FSTR;
      float f[8];
      int p = 0;
      #pragma unroll
      for (int i = 0; i < ND; ++i) {
        #pragma unroll
        for (int j = i; j < ND; ++j) {
          if (i == 9 && j == 9) continue;
          f[p & 7] = svc[i] * svc[j];
          if ((p & 7) == 7) {
            intx4 v;
            v.x = (int)pack_bf16(f[0], f[1]);
            v.y = (int)pack_bf16(f[2], f[3]);
            v.z = (int)pack_bf16(f[4], f[5]);
            v.w = (int)pack_bf16(f[6], f[7]);
            *(intx4*)&lds[rb + (p >> 3) * 4] = v;
          }
          ++p;
        }
      }
      #pragma unroll
      for (int i = 0; i < ND; ++i) {
        f[p & 7] = svc[i];
        if ((p & 7) == 7) {
          intx4 v;
          v.x = (int)pack_bf16(f[0], f[1]);
          v.y = (int)pack_bf16(f[2], f[3]);
          v.z = (int)pack_bf16(f[4], f[5]);
          v.w = (int)pack_bf16(f[6], f[7]);
          *(intx4*)&lds[rb + (p >> 3) * 4] = v;
        }
        ++p;
      }
    }

    // block-uniform work-queue grab (thread 0 only)
    if (tid == 0) nextc_sh = (int)atomicAdd(queue, 1u);

    __syncthreads();   // feat ready + nextc broadcast

    int nextc = nextc_sh;

    // prefetch next chunk's inputs (overlaps MFMA/scatter/epilogue)
    float svn[ND];
    int ktn;
    {
      int cc = nextc < NCHUNK ? nextc : (NCHUNK - 1);
      int n = cc * 256 + tid;
      int nc = n < NSPK ? n : (NSPK - 1);
      const float2* srow = (const float2*)(s + (size_t)nc * ND);
      #pragma unroll
      for (int i = 0; i < 5; ++i) {
        float2 v2 = srow[i];
        svn[2 * i] = v2.x;
        svn[2 * i + 1] = v2.y;
      }
      ktn = ks[nc] * NT + ts[nc];
    }

    // MFMA: D[spike][c] = F x (Whi + Wlo)
    floatx4 accf[4][2];
    #pragma unroll
    for (int mt = 0; mt < 4; ++mt)
      #pragma unroll
      for (int nt = 0; nt < 2; ++nt)
        accf[mt][nt] = (floatx4){0.f, 0.f, 0.f, 0.f};

    #pragma unroll
    for (int mt = 0; mt < 4; ++mt) {
      #pragma unroll
      for (int ks2 = 0; ks2 < 2; ++ks2) {
        FragCvt a;
        a.i = *(const intx4*)&lds[(wv_ * 64 + mt * 16 + r) * FSTR + ks2 * 16 + q * 4];
        #pragma unroll
        for (int nt = 0; nt < 2; ++nt) {
          accf[mt][nt] = __builtin_amdgcn_mfma_f32_16x16x32_bf16(
              a.s, bf[0][nt][ks2].s, accf[mt][nt], 0, 0, 0);
          accf[mt][nt] = __builtin_amdgcn_mfma_f32_16x16x32_bf16(
              a.s, bf[1][nt][ks2].s, accf[mt][nt], 0, 0, 0);
        }
      }
    }

    __syncthreads();   // all feat reads done -> safe to overwrite with logits

    // scatter C-frags to LDS logits[spike][c]  (row = q*4+reg, col = r)
    #pragma unroll
    for (int mt = 0; mt < 4; ++mt)
      #pragma unroll
      for (int nt = 0; nt < 2; ++nt)
        #pragma unroll
        for (int rr = 0; rr < 4; ++rr) {
          int srow_ = wv_ * 64 + mt * 16 + q * 4 + rr;
          lds[srow_ * FSTR + nt * 16 + r] = __float_as_int(accf[mt][nt][rr]);
        }
    __syncthreads();

    // epilogue: logits += lp + cst + w99*s9^2 ; logsumexp
    {
      // fp16 lp gather: 64 B row = 4 x dwordx4
      const intx4* lpp = (const intx4*)(pisT + (size_t)ktc * NC);
      intx4 lraw[4];
      #pragma unroll
      for (int i = 0; i < 4; ++i) lraw[i] = lpp[i];

      float s9sq = svc[9] * svc[9];
      int base = tid * FSTR;
      float lg[32];
      #pragma unroll
      for (int g = 0; g < 8; ++g) {
        intx4 lv = *(const intx4*)&lds[base + g * 4];
        lg[4 * g + 0] = __int_as_float(lv.x);
        lg[4 * g + 1] = __int_as_float(lv.y);
        lg[4 * g + 2] = __int_as_float(lv.z);
        lg[4 * g + 3] = __int_as_float(lv.w);
      }
      #pragma unroll
      for (int g = 0; g < 16; ++g) {
        H2Cvt hc;
        hc.i = ((const int*)lraw)[g];
        float lo = __low2float(hc.h), hi = __high2float(hc.h);
        lg[2 * g + 0] += lo + fmaf(cpack[32 + 2 * g + 0], s9sq, cpack[2 * g + 0]);
        lg[2 * g + 1] += hi + fmaf(cpack[32 + 2 * g + 1], s9sq, cpack[2 * g + 1]);
      }

      float m = lg[0];
      #pragma unroll
      for (int c = 1; c < 32; ++c) m = fmaxf(m, lg[c]);
      float ssum = 0.f;
      #pragma unroll
      for (int c = 0; c < 32; ++c) ssum += __expf(lg[c] - m);
      if (ncur < NSPK) lse_sum += m + __logf(ssum);
    }

    // rotate prefetched chunk into place
    chunk = nextc;
    ktc = ktn;
    #pragma unroll
    for (int i = 0; i < ND; ++i) svc[i] = svn[i];
  }

  // block reduction -> one fp64 atomic per block
  #pragma unroll
  for (int off = 32; off > 0; off >>= 1) lse_sum += __shfl_down(lse_sum, off);
  if ((tid & 63) == 0) red[tid >> 6] = lse_sum;
  __syncthreads();
  if (tid == 0) {
    atomicAdd(acc, (double)(red[0] + red[1] + red[2] + red[3]));
    __threadfence();
    unsigned int old = atomicAdd(counter, 1u);
    if (old == GRID - 1) {
      __threadfence();
      double v = atomicAdd(acc, 0.0);
      out[0] = (float)v;
    }
  }
}

extern "C" void kernel_launch(void* const* d_in, const int* in_sizes, int n_in,
                              void* d_out, int out_size, void* d_ws, size_t ws_size,
                              hipStream_t stream) {
  const float* s       = (const float*)d_in[0];
  const float* y       = (const float*)d_in[1];
  const int*   ks      = (const int*)d_in[2];
  const int*   ts      = (const int*)d_in[3];
  const float* means   = (const float*)d_in[4];
  const float* covs    = (const float*)d_in[5];
  const float* b_mu    = (const float*)d_in[6];
  const float* b_ls    = (const float*)d_in[7];
  const float* beta_mu = (const float*)d_in[8];
  const float* beta_ls = (const float*)d_in[9];
  float* out = (float*)d_out;

  char* ws = (char*)d_ws;
  double* acc           = (double*)ws;
  unsigned int* counter = (unsigned int*)(ws + 8);
  unsigned int* queue   = (unsigned int*)(ws + 12);
  float* cpack          = (float*)(ws + 64);
  int* wt               = (int*)(ws + 1024);
  __half* pisT          = (__half*)(ws + 16384);

  prep_kernel<<<2 + (NK * NT) / 256, 256, 0, stream>>>(
      y, means, covs, b_mu, b_ls, beta_mu, beta_ls, wt, cpack, pisT, acc,
      counter, queue);
  spike_kernel<<<GRID, 256, 0, stream>>>(
      s, ks, ts, wt, cpack, pisT, acc, counter, queue, out);
}

// Round 7
// 168.777 us; speedup vs baseline: 1.0015x; 1.0015x over previous
//
#include <hip/hip_runtime.h>
#include <hip/hip_bf16.h>
#include <hip/hip_fp16.h>
#include <math.h>

#define NK 256
#define NT 128
#define NC 32
#define ND 10
#define NSPK 1000000
#define LOG2PI 1.8378770664093453f
#define NWCHUNK (NSPK / 64)          // 15625 wave-chunks of 64 spikes (exact)
#define GRID 1024                    // 4 blocks/CU
#define NWAVES (GRID * 4)            // 4096 autonomous waves
#define LSTR 33                      // dwords per LDS row (odd -> <=2-4 way conflicts)

typedef __attribute__((ext_vector_type(8))) short short8;
typedef __attribute__((ext_vector_type(4))) float floatx4;
typedef __attribute__((ext_vector_type(4))) int intx4;

union FragCvt { intx4 i; short8 s; };
union H2Cvt { int i; __half2 h; };

// ws layout:
//   [0,8)      double acc
//   [8,12)     uint done-counter
//   [64,320)   float cpack[64] : [c]=cst_c, [32+c]=w99_c
//   [1024,..)  int wt[64][32]  : bf16-pair-packed W, rows 0..31 hi, 32..63 lo
//   [16384,..) __half pisT[NK*NT][32] : fp16 (log_pi + cst), 64 B rows

__device__ inline unsigned pack_bf16(float a, float b) {
  __hip_bfloat16 ha = __float2bfloat16(a), hb = __float2bfloat16(b);
  unsigned short ua, ub;
  __builtin_memcpy(&ua, &ha, 2);
  __builtin_memcpy(&ub, &hb, 2);
  return (unsigned)ua | ((unsigned)ub << 16);
}

// ============================ PREP 1: coefs + scalars ======================
__global__ void prep1_kernel(const float* __restrict__ means,
                             const float* __restrict__ covs,
                             const float* __restrict__ b_mu,
                             const float* __restrict__ b_ls,
                             const float* __restrict__ beta_mu,
                             const float* __restrict__ beta_ls,
                             int* __restrict__ wt,
                             float* __restrict__ cpack,
                             double* __restrict__ acc,
                             unsigned int* __restrict__ counter) {
  int blk = blockIdx.x;
  int tid = threadIdx.x;

  if (blk == 0) {
    int c = tid;
    if (c >= NC) return;

    float M[ND][ND];
    #pragma unroll
    for (int i = 0; i < ND; ++i)
      #pragma unroll
      for (int j = 0; j < ND; ++j)
        M[i][j] = covs[c * ND * ND + i * ND + j];

    // Cholesky, lower triangle in place
    float logdet = 0.f;
    #pragma unroll
    for (int j = 0; j < ND; ++j) {
      float d = M[j][j];
      #pragma unroll
      for (int k = 0; k < ND; ++k) if (k < j) d -= M[j][k] * M[j][k];
      float sq = sqrtf(d);
      M[j][j] = sq;
      logdet += 2.f * __logf(sq);
      float inv = 1.f / sq;
      #pragma unroll
      for (int i = 0; i < ND; ++i) {
        if (i > j) {
          float s2 = M[i][j];
          #pragma unroll
          for (int k = 0; k < ND; ++k) if (k < j) s2 -= M[i][k] * M[j][k];
          M[i][j] = s2 * inv;
        }
      }
    }

    // invert lower triangle in place: M(lower) := L^-1
    #pragma unroll
    for (int j = 0; j < ND; ++j) {
      M[j][j] = 1.f / M[j][j];
      #pragma unroll
      for (int i = 0; i < ND; ++i) {
        if (i > j) {
          float s2 = 0.f;
          #pragma unroll
          for (int k = 0; k < ND; ++k) if (k >= j && k < i) s2 += M[i][k] * M[k][j];
          M[i][j] = -s2 / M[i][i];
        }
      }
    }

    // P = Li^T Li : off-diag -> upper triangle of M, diag -> pd[]
    float pd[ND];
    #pragma unroll
    for (int i = 0; i < ND; ++i) {
      #pragma unroll
      for (int jj = 0; jj < ND; ++jj) {
        if (jj >= i) {
          float s2 = 0.f;
          #pragma unroll
          for (int k = 0; k < ND; ++k) if (k >= jj) s2 += M[k][i] * M[k][jj];
          if (jj > i) M[i][jj] = s2;
          else pd[i] = s2;
        }
      }
    }

    float mu[ND], qv[ND];
    #pragma unroll
    for (int i = 0; i < ND; ++i) mu[i] = means[c * ND + i];
    float muPmu = 0.f;
    #pragma unroll
    for (int i = 0; i < ND; ++i) {
      float a2 = pd[i] * mu[i];
      #pragma unroll
      for (int j = 0; j < ND; ++j) {
        if (j < i) a2 += M[j][i] * mu[j];
        if (j > i) a2 += M[i][j] * mu[j];
      }
      qv[i] = a2;
      muPmu += mu[i] * a2;
    }
    float cst = -0.5f * ((float)ND * LOG2PI + logdet + muPmu);

    // K=64 coefficient vector: 54 pairs (i<=j except (9,9)) + 10 linear
    float wv[64];
    int p = 0;
    #pragma unroll
    for (int i = 0; i < ND; ++i)
      #pragma unroll
      for (int j = 0; j < ND; ++j)
        if (j >= i && !(i == 9 && j == 9))
          wv[p++] = (i == j) ? -0.5f * pd[i] : -M[i][j];
    #pragma unroll
    for (int i = 0; i < ND; ++i) wv[54 + i] = qv[i];

    // hi/lo split, bf16-pair pack; rows of 32 dwords (128B)
    #pragma unroll
    for (int j = 0; j < 32; ++j) {
      float a = wv[2 * j], b = wv[2 * j + 1];
      float ah = __bfloat162float(__float2bfloat16(a));
      float bh = __bfloat162float(__float2bfloat16(b));
      wt[c * 32 + j] = (int)pack_bf16(ah, bh);
      wt[(32 + c) * 32 + j] = (int)pack_bf16(a - ah, b - bh);
    }
    cpack[c] = cst;
    cpack[32 + c] = -0.5f * pd[9];   // w99

  } else {
    // prior - q scalar terms -> plain-store acc, init counter
    float local = 0.f;
    for (int i = tid; i < NC; i += 256)
      local += fmaf(-0.5f * b_mu[i], b_mu[i], b_ls[i]);
    for (int i = tid; i < NC * NT; i += 256)
      local += fmaf(-0.5f * beta_mu[i], beta_mu[i], beta_ls[i]);
    #pragma unroll
    for (int off = 32; off > 0; off >>= 1) local += __shfl_down(local, off);
    __shared__ float red[4];
    if ((tid & 63) == 0) red[tid >> 6] = local;
    __syncthreads();
    if (tid == 0) {
      acc[0] = (double)(red[0] + red[1] + red[2] + red[3]);
      counter[0] = 0u;
    }
  }
}

// ============== PREP 2: log-softmax pis table w/ cst folded (fp16) =========
__global__ void prep2_kernel(const float* __restrict__ y,
                             const float* __restrict__ b_mu,
                             const float* __restrict__ beta_mu,
                             const float* __restrict__ cpack,
                             __half* __restrict__ pisT) {
  int id = blockIdx.x * 256 + threadIdx.x;   // id = k*NT + t
  int t = id & (NT - 1);
  float yv = y[id];
  float v[NC];
  float m = -1e30f;
  #pragma unroll
  for (int c = 0; c < NC; ++c) {
    v[c] = fmaf(beta_mu[c * NT + t], yv, b_mu[c]);
    m = fmaxf(m, v[c]);
  }
  float ssum = 0.f;
  #pragma unroll
  for (int c = 0; c < NC; ++c) ssum += __expf(v[c] - m);
  float lz = m + __logf(ssum);
  __half* outp = pisT + (size_t)id * NC;
  #pragma unroll
  for (int c = 0; c < NC; ++c) outp[c] = __float2half(v[c] - lz + cpack[c]);
}

// =============== MAIN: barrier-free wave-autonomous MFMA ===================
__global__ void __launch_bounds__(256)
__attribute__((amdgpu_waves_per_eu(4, 4)))
spike_kernel(const float* __restrict__ s,
             const int* __restrict__ ks,
             const int* __restrict__ ts,
             const int* __restrict__ wt,
             const float* __restrict__ cpack,
             const __half* __restrict__ pisT,
             double* __restrict__ acc,
             unsigned int* __restrict__ counter,
             float* __restrict__ out) {
  __shared__ int lds[4 * 64 * LSTR];   // 33.8 KB: one 64x33 region per wave
  __shared__ float red[4];

  int tid = threadIdx.x;
  int wid = tid >> 6, L = tid & 63;
  int r = L & 15, q = L >> 4;
  int* ldsw = &lds[wid * 64 * LSTR];

  // W as MFMA A-operand (comps = M): lane (r,q) holds W[mt*16+r][ks*32+q*8+j]
  FragCvt wf[2][2][2];   // [h][mt][ks]
  #pragma unroll
  for (int h = 0; h < 2; ++h)
    #pragma unroll
    for (int mt = 0; mt < 2; ++mt)
      #pragma unroll
      for (int kk = 0; kk < 2; ++kk)
        wf[h][mt][kk].i =
            *(const intx4*)&wt[(h * 32 + mt * 16 + r) * 32 + kk * 16 + q * 4];

  float w99v[NC];
  #pragma unroll
  for (int c = 0; c < NC; ++c) w99v[c] = cpack[32 + c];   // uniform -> SGPRs

  float lse_sum = 0.f;
  int g = blockIdx.x * 4 + wid;        // global wave id, static schedule

  // prologue: first chunk's inputs
  int c = g;
  float svc[ND];
  int kvc, tvc;
  {
    int n = c * 64 + L;
    const float2* srow = (const float2*)(s + (size_t)n * ND);
    #pragma unroll
    for (int i = 0; i < 5; ++i) {
      float2 v2 = srow[i];
      svc[2 * i] = v2.x;
      svc[2 * i + 1] = v2.y;
    }
    kvc = ks[n];
    tvc = ts[n];
  }

  while (c < NWCHUNK) {
    // issue pisT gather for current chunk immediately (consumed in epilogue)
    int ktc = kvc * NT + tvc;
    const intx4* lpp = (const intx4*)(pisT + (size_t)ktc * NC);
    intx4 lraw[4];
    #pragma unroll
    for (int i = 0; i < 4; ++i) lraw[i] = lpp[i];

    // build K=64 bf16 feature row for own spike -> wave-private LDS row L
    {
      int rb = L * LSTR;
      float f[8];
      int p = 0;
      #pragma unroll
      for (int i = 0; i < ND; ++i) {
        #pragma unroll
        for (int j = i; j < ND; ++j) {
          if (i == 9 && j == 9) continue;
          f[p & 7] = svc[i] * svc[j];
          if ((p & 7) == 7) {
            intx4 v;
            v.x = (int)pack_bf16(f[0], f[1]);
            v.y = (int)pack_bf16(f[2], f[3]);
            v.z = (int)pack_bf16(f[4], f[5]);
            v.w = (int)pack_bf16(f[6], f[7]);
            *(intx4*)&ldsw[rb + (p >> 3) * 4] = v;
          }
          ++p;
        }
      }
      #pragma unroll
      for (int i = 0; i < ND; ++i) {
        f[p & 7] = svc[i];
        if ((p & 7) == 7) {
          intx4 v;
          v.x = (int)pack_bf16(f[0], f[1]);
          v.y = (int)pack_bf16(f[2], f[3]);
          v.z = (int)pack_bf16(f[4], f[5]);
          v.w = (int)pack_bf16(f[6], f[7]);
          *(intx4*)&ldsw[rb + (p >> 3) * 4] = v;
        }
        ++p;
      }
    }

    // prefetch next chunk's inputs (consumed next iteration; no barrier
    // ever drains these)
    int c2 = c + NWAVES;
    float svn[ND];
    int kvn, tvn;
    {
      int cc = c2 < NWCHUNK ? c2 : 0;
      int n2 = cc * 64 + L;
      const float2* srow = (const float2*)(s + (size_t)n2 * ND);
      #pragma unroll
      for (int i = 0; i < 5; ++i) {
        float2 v2 = srow[i];
        svn[2 * i] = v2.x;
        svn[2 * i + 1] = v2.y;
      }
      kvn = ks[n2];
      tvn = ts[n2];
    }

    // MFMA: D[comp][spike] = W x F  (wave-private LDS reads, in-order DS)
    floatx4 accf[2][4];   // [mt][nt]
    #pragma unroll
    for (int mt = 0; mt < 2; ++mt)
      #pragma unroll
      for (int nt = 0; nt < 4; ++nt)
        accf[mt][nt] = (floatx4){0.f, 0.f, 0.f, 0.f};

    #pragma unroll
    for (int nt = 0; nt < 4; ++nt) {
      FragCvt b0, b1;
      b0.i = *(const intx4*)&ldsw[(nt * 16 + r) * LSTR + q * 4];
      b1.i = *(const intx4*)&ldsw[(nt * 16 + r) * LSTR + 16 + q * 4];
      #pragma unroll
      for (int mt = 0; mt < 2; ++mt) {
        accf[mt][nt] = __builtin_amdgcn_mfma_f32_16x16x32_bf16(
            wf[0][mt][0].s, b0.s, accf[mt][nt], 0, 0, 0);
        accf[mt][nt] = __builtin_amdgcn_mfma_f32_16x16x32_bf16(
            wf[1][mt][0].s, b0.s, accf[mt][nt], 0, 0, 0);
        accf[mt][nt] = __builtin_amdgcn_mfma_f32_16x16x32_bf16(
            wf[0][mt][1].s, b1.s, accf[mt][nt], 0, 0, 0);
        accf[mt][nt] = __builtin_amdgcn_mfma_f32_16x16x32_bf16(
            wf[1][mt][1].s, b1.s, accf[mt][nt], 0, 0, 0);
      }
    }

    // transpose via wave-private LDS: logits[spike local][comp]
    // lane holds D[comp = mt*16+q*4+rr][spike = nt*16+r]
    #pragma unroll
    for (int nt = 0; nt < 4; ++nt)
      #pragma unroll
      for (int mt = 0; mt < 2; ++mt)
        *(floatx4*)&ldsw[(nt * 16 + r) * LSTR + mt * 16 + q * 4] = accf[mt][nt];

    // epilogue: own row L -> logsumexp
    {
      int rb = L * LSTR;
      float lg[NC];
      #pragma unroll
      for (int gch = 0; gch < 8; ++gch) {
        intx4 lv = *(const intx4*)&ldsw[rb + gch * 4];
        lg[4 * gch + 0] = __int_as_float(lv.x);
        lg[4 * gch + 1] = __int_as_float(lv.y);
        lg[4 * gch + 2] = __int_as_float(lv.z);
        lg[4 * gch + 3] = __int_as_float(lv.w);
      }
      float s9sq = svc[9] * svc[9];
      #pragma unroll
      for (int gg = 0; gg < 16; ++gg) {
        H2Cvt hc;
        hc.i = ((const int*)lraw)[gg];
        lg[2 * gg + 0] += __low2float(hc.h) + w99v[2 * gg + 0] * s9sq;
        lg[2 * gg + 1] += __high2float(hc.h) + w99v[2 * gg + 1] * s9sq;
      }

      float m = lg[0];
      #pragma unroll
      for (int cc = 1; cc < NC; ++cc) m = fmaxf(m, lg[cc]);
      float ssum = 0.f;
      #pragma unroll
      for (int cc = 0; cc < NC; ++cc) ssum += __expf(lg[cc] - m);
      lse_sum += m + __logf(ssum);
    }

    // rotate prefetched inputs
    c = c2;
    kvc = kvn;
    tvc = tvn;
    #pragma unroll
    for (int i = 0; i < ND; ++i) svc[i] = svn[i];
  }

  // block reduction -> one fp64 atomic per block (single barrier, end only)
  #pragma unroll
  for (int off = 32; off > 0; off >>= 1) lse_sum += __shfl_down(lse_sum, off);
  if ((tid & 63) == 0) red[tid >> 6] = lse_sum;
  __syncthreads();
  if (tid == 0) {
    atomicAdd(acc, (double)(red[0] + red[1] + red[2] + red[3]));
    __threadfence();
    unsigned int old = atomicAdd(counter, 1u);
    if (old == GRID - 1) {
      __threadfence();
      double v = atomicAdd(acc, 0.0);
      out[0] = (float)v;
    }
  }
}

extern "C" void kernel_launch(void* const* d_in, const int* in_sizes, int n_in,
                              void* d_out, int out_size, void* d_ws, size_t ws_size,
                              hipStream_t stream) {
  const float* s       = (const float*)d_in[0];
  const float* y       = (const float*)d_in[1];
  const int*   ks      = (const int*)d_in[2];
  const int*   ts      = (const int*)d_in[3];
  const float* means   = (const float*)d_in[4];
  const float* covs    = (const float*)d_in[5];
  const float* b_mu    = (const float*)d_in[6];
  const float* b_ls    = (const float*)d_in[7];
  const float* beta_mu = (const float*)d_in[8];
  const float* beta_ls = (const float*)d_in[9];
  float* out = (float*)d_out;

  char* ws = (char*)d_ws;
  double* acc           = (double*)ws;
  unsigned int* counter = (unsigned int*)(ws + 8);
  float* cpack          = (float*)(ws + 64);
  int* wt               = (int*)(ws + 1024);
  __half* pisT          = (__half*)(ws + 16384);

  prep1_kernel<<<2, 256, 0, stream>>>(
      means, covs, b_mu, b_ls, beta_mu, beta_ls, wt, cpack, acc, counter);
  prep2_kernel<<<(NK * NT) / 256, 256, 0, stream>>>(
      y, b_mu, beta_mu, cpack, pisT);
  spike_kernel<<<GRID, 256, 0, stream>>>(
      s, ks, ts, wt, cpack, pisT, acc, counter, out);
}